// Round 7
// baseline (41.499 us; speedup 1.0000x reference)
//
#include <hip/hip_runtime.h>
#include <hip/hip_bf16.h>
#include <stdint.h>

// KANLinear: y[b,o] = sum_{d,k} coeff[b,d,k]*values[o,d,k] + xc@skip_w^T + skip_b
//   Vp[o,d*16+k] = values[o,d,k] + grid[k]*skip_w[o,d]   (prep, bf16)
//   y = A @ Vp^T + skip_b  (MFMA GEMM  M=8192 N=256 K=4096)
// Round 7: TLP fix - 2 independent blocks/CU. BM=128 BN=128, 256 thr
//          (4 waves of 64x64), KSPLIT=4 -> grid 512. B direct from L2
//          (chunk-transposed Vp), A via LDS dbuf (32KB), partials+reduce
//          (no atomics), s_setprio around MFMA.

#define D_DIM  256
#define O_DIM  256
#define BM     128
#define BK     64
#define NTHR   256

typedef __attribute__((ext_vector_type(8))) short bf16x8;
typedef __attribute__((ext_vector_type(4))) float f32x4;

// ---------------------------------------------------------------------------
// Prep: Vp chunk-transposed: chunk c = kflat>>3 (0..511) of 8 bf16 (16B);
// stored at Vp[(c*256 + o)*8] so a B-fragment (16 consecutive o at one chunk)
// is a 256B-coalesced load per 16-lane group.
// ---------------------------------------------------------------------------
__global__ __launch_bounds__(256) void kan_prep(
    const float* __restrict__ values,   // [O][D][K]
    const float* __restrict__ skip_w,   // [O][D]
    const float* __restrict__ gknots,   // [K]
    unsigned short* __restrict__ Vp)    // 2 MB bf16, chunk-transposed
{
    int tid = blockIdx.x * blockDim.x + threadIdx.x;    // 0..131071
    int e = tid * 8;
    int o = e >> 12;
    int kflat = e & 4095;
    float sw = skip_w[(o << 8) | (kflat >> 4)];
    int kmod = kflat & 15;                              // 0 or 8

    const float4* vp4 = reinterpret_cast<const float4*>(values + e);
    float4 v0 = vp4[0], v1 = vp4[1];
    float f[8] = {v0.x, v0.y, v0.z, v0.w, v1.x, v1.y, v1.z, v1.w};
    unsigned int w[4];
#pragma unroll
    for (int j = 0; j < 4; ++j) {
        float2 ab;
        ab.x = f[2*j]     + gknots[kmod + 2*j]     * sw;
        ab.y = f[2*j + 1] + gknots[kmod + 2*j + 1] * sw;
        __hip_bfloat162 p2 = __float22bfloat162_rn(ab);
        __builtin_memcpy(&w[j], &p2, 4);
    }
    size_t c = (size_t)(kflat >> 3) * 256 + (size_t)o;
    *reinterpret_cast<uint4*>(Vp + c * 8) = make_uint4(w[0], w[1], w[2], w[3]);
}

// ---------------------------------------------------------------------------
// GEMM: BM=128 x BN=128 x BK=64, 256 thr = 4 waves (2m x 2n), wave-tile
// 64x64 (acc[4][4]). A via LDS dbuf (XOR swizzle); B global->reg 1-deep
// prefetch. Partial f32 store per K-slice.
// ---------------------------------------------------------------------------
template<int KS>
__global__ __launch_bounds__(NTHR, 2) void kan_gemm(
    const float* __restrict__ x,          // [B][D] f32
    const unsigned short* __restrict__ Vp,
    float* __restrict__ part)             // [KS][8192][256] f32
{
    __shared__ unsigned short As[2][BM * BK];   // 2 x 16 KB

    constexpr int ITERS = 64 / KS;
    const int t    = threadIdx.x;
    const int lane = t & 63;
    const int wid  = t >> 6;
    const int wm   = wid >> 1;         // 0..1 (64 rows)
    const int wn   = wid & 1;          // 0..1 (64 cols)
    const int l15  = lane & 15;
    const int lhi  = lane >> 4;        // 0..3

    const int bid = (int)blockIdx.x;
    const int ks  = bid & (KS - 1);
    const int nt  = (bid / KS) & 1;
    const int mt  = bid / (2 * KS);
    const int bm0 = mt * BM;
    const int nc0 = nt * 128;
    const size_t kc0 = (size_t)ks * (512 / KS);   // global 16B-chunk base

    // A staging: thread -> row ar (0..127), d-pair base ad2 (0 or 2)
    const int ar  = t >> 1;
    const int ad2 = (t & 1) * 2;
    const float* xp = x + (size_t)(bm0 + ar) * D_DIM + ks * (256 / KS) + ad2;

    char* arow[2] = { (char*)&As[0][0] + ar * 128, (char*)&As[1][0] + ar * 128 };
    const int cs0 = ((2 * ad2)     ^ (ar & 7)) * 16;
    const int cs1 = ((2 * ad2 + 1) ^ (ar & 7)) * 16;
    const int cs2 = ((2 * ad2 + 2) ^ (ar & 7)) * 16;
    const int cs3 = ((2 * ad2 + 3) ^ (ar & 7)) * 16;

    // one x value -> 16 bf16 interp coeffs (8 dwords), pair at knots li,li+1
    auto buildwd = [&](float xv, unsigned int* wd) {
        float xc = fminf(1.f, fmaxf(-1.f, xv));
        float tt = (xc + 1.f) * 7.5f;            // (xc - g0)/h, h = 2/15
        int li = (int)tt;
        li = li > 14 ? 14 : li;
        float w1 = tt - (float)li;
        float2 cw; cw.x = 1.f - w1; cw.y = w1;
        __hip_bfloat162 p2 = __float22bfloat162_rn(cw);   // v_cvt_pk_bf16_f32
        unsigned int pk;
        __builtin_memcpy(&pk, &p2, 4);
        unsigned long long w64 = (unsigned long long)pk << ((li & 1) * 16);
        unsigned int lo = (unsigned int)w64;
        unsigned int hi = (unsigned int)(w64 >> 32);
        int jl = li >> 1;
#pragma unroll
        for (int j = 0; j < 8; ++j)
            wd[j] = (j == jl) ? lo : ((j == jl + 1) ? hi : 0u);
    };

    auto stageA = [&](int buf, float2 xv) {
        unsigned int wd[8];
        char* a = arow[buf];
        buildwd(xv.x, wd);
        *reinterpret_cast<uint4*>(a + cs0) = make_uint4(wd[0], wd[1], wd[2], wd[3]);
        *reinterpret_cast<uint4*>(a + cs1) = make_uint4(wd[4], wd[5], wd[6], wd[7]);
        buildwd(xv.y, wd);
        *reinterpret_cast<uint4*>(a + cs2) = make_uint4(wd[0], wd[1], wd[2], wd[3]);
        *reinterpret_cast<uint4*>(a + cs3) = make_uint4(wd[4], wd[5], wd[6], wd[7]);
    };

    // B fragment loads: frag (kh, ni): chunk kc0 + KT*8 + kh*4 + lhi,
    // col n = nc0 + wn*64 + ni*16 + l15.
    #define LOADB(BG, KT)                                                      \
        {                                                                      \
            const unsigned short* _b = Vp + (kc0 + (size_t)(KT) * 8) * 2048;   \
            _Pragma("unroll")                                                  \
            for (int kh = 0; kh < 2; ++kh)                                     \
                _Pragma("unroll")                                              \
                for (int ni = 0; ni < 4; ++ni) {                               \
                    int n = nc0 + wn * 64 + ni * 16 + l15;                     \
                    BG[kh * 4 + ni] = *reinterpret_cast<const bf16x8*>(        \
                        _b + ((size_t)((kh * 4 + lhi) * 256 + n)) * 8);        \
                }                                                              \
        }

    f32x4 acc[4][4] = {};
    bf16x8 bgA[8], bgB[8];

    int abyte[4], a7[4];
#pragma unroll
    for (int mi = 0; mi < 4; ++mi) {
        int m = wm * 64 + mi * 16 + l15;
        abyte[mi] = m * 128;
        a7[mi] = m & 7;
    }

    // ---- prologue
    float2 x1 = *reinterpret_cast<const float2*>(xp);
    LOADB(bgA, 0);
    float2 xn = (ITERS > 1) ? *reinterpret_cast<const float2*>(xp + 4) : x1;
    stageA(0, x1);
    asm volatile("s_waitcnt lgkmcnt(0)" ::: "memory");
    __builtin_amdgcn_s_barrier();
    __builtin_amdgcn_sched_barrier(0);

    #define ITERBODY(KT, CUR, BGC, BGN)                                       \
        {                                                                     \
            const bool last = (KT) == ITERS - 1;                              \
            if (!last) LOADB(BGN, (KT) + 1);                                  \
            const char* Ab = (const char*)&As[CUR][0];                        \
            bf16x8 af[4];                                                     \
            /* kh = 0 */                                                      \
            _Pragma("unroll")                                                 \
            for (int mi = 0; mi < 4; ++mi)                                    \
                af[mi] = *reinterpret_cast<const bf16x8*>(                    \
                    Ab + abyte[mi] + ((lhi ^ a7[mi]) << 4));                  \
            __builtin_amdgcn_s_setprio(1);                                    \
            _Pragma("unroll")                                                 \
            for (int mi = 0; mi < 4; ++mi)                                    \
                _Pragma("unroll")                                             \
                for (int ni = 0; ni < 4; ++ni)                                \
                    acc[mi][ni] = __builtin_amdgcn_mfma_f32_16x16x32_bf16(    \
                        af[mi], BGC[ni], acc[mi][ni], 0, 0, 0);               \
            __builtin_amdgcn_s_setprio(0);                                    \
            if (!last) {                                                      \
                stageA((CUR) ^ 1, xn);                                        \
                if ((KT) + 2 < ITERS)                                         \
                    xn = *reinterpret_cast<const float2*>(xp + ((KT) + 2) * 4);\
            }                                                                 \
            /* kh = 1 */                                                      \
            _Pragma("unroll")                                                 \
            for (int mi = 0; mi < 4; ++mi)                                    \
                af[mi] = *reinterpret_cast<const bf16x8*>(                    \
                    Ab + abyte[mi] + (((4 + lhi) ^ a7[mi]) << 4));            \
            __builtin_amdgcn_s_setprio(1);                                    \
            _Pragma("unroll")                                                 \
            for (int mi = 0; mi < 4; ++mi)                                    \
                _Pragma("unroll")                                             \
                for (int ni = 0; ni < 4; ++ni)                                \
                    acc[mi][ni] = __builtin_amdgcn_mfma_f32_16x16x32_bf16(    \
                        af[mi], BGC[4 + ni], acc[mi][ni], 0, 0, 0);           \
            __builtin_amdgcn_s_setprio(0);                                    \
            if (!last) {                                                      \
                asm volatile("s_waitcnt lgkmcnt(0)" ::: "memory");            \
                __builtin_amdgcn_s_barrier();                                 \
                __builtin_amdgcn_sched_barrier(0);                            \
            }                                                                 \
        }

    for (int t2 = 0; t2 < ITERS / 2; ++t2) {
        ITERBODY(2 * t2,     0, bgA, bgB);
        ITERBODY(2 * t2 + 1, 1, bgB, bgA);
    }
    #undef ITERBODY
    #undef LOADB

    // ---- epilogue: partial store (bias added in reduce)
    float* dst = part + (size_t)ks * (8192 * 256);
#pragma unroll
    for (int ni = 0; ni < 4; ++ni) {
        int col = nc0 + wn * 64 + ni * 16 + l15;
#pragma unroll
        for (int mi = 0; mi < 4; ++mi) {
            f32x4 v = acc[mi][ni];
            int row0 = bm0 + wm * 64 + mi * 16 + lhi * 4;
#pragma unroll
            for (int r = 0; r < 4; ++r)
                dst[(size_t)(row0 + r) * O_DIM + col] = v[r];
        }
    }
}

// ---------------------------------------------------------------------------
// Reduce: out = sum_p part[p] + skip_b  (vectorized f32x4)
// ---------------------------------------------------------------------------
__global__ __launch_bounds__(256) void kan_reduce(
    const float* __restrict__ part,   // [nparts][8192][256]
    const float* __restrict__ skip_b, // [256]
    float* __restrict__ out,          // [8192][256]
    int nparts)
{
    size_t i4 = (size_t)blockIdx.x * 256 + threadIdx.x;   // float4 index
    size_t e = i4 * 4;
    f32x4 s = *reinterpret_cast<const f32x4*>(&skip_b[e & 255]);
    for (int p = 0; p < nparts; ++p)
        s += *reinterpret_cast<const f32x4*>(part + (size_t)p * (8192 * 256) + e);
    *reinterpret_cast<f32x4*>(out + e) = s;
}

extern "C" void kernel_launch(void* const* d_in, const int* in_sizes, int n_in,
                              void* d_out, int out_size, void* d_ws, size_t ws_size,
                              hipStream_t stream) {
    const float* x      = (const float*)d_in[0];   // [8192][256]
    const float* values = (const float*)d_in[1];   // [256][256][16]
    const float* skip_w = (const float*)d_in[2];   // [256][256]
    const float* skip_b = (const float*)d_in[3];   // [256]
    const float* gknots = (const float*)d_in[4];   // [16]
    float* out = (float*)d_out;
    (void)in_sizes; (void)n_in; (void)out_size;

    unsigned short* Vp = (unsigned short*)d_ws;                    // 2 MB
    float* part = (float*)((char*)d_ws + 2 * 1024 * 1024);         // partials

    kan_prep<<<dim3(512), dim3(256), 0, stream>>>(values, skip_w, gknots, Vp);

    const size_t need4 = 2u * 1024 * 1024 + (size_t)4 * 8192 * 256 * 4;
    if (ws_size >= need4) {
        // 64 mt x 2 nt x 4 ks = 512 blocks x 256 thr = 2 blocks/CU (TLP)
        kan_gemm<4><<<dim3(512), dim3(NTHR), 0, stream>>>(x, Vp, part);
        kan_reduce<<<dim3(2048), dim3(256), 0, stream>>>(part, skip_b, out, 4);
    } else {
        // fallback: no K-split; partial lives in out, reduce adds bias in-place
        kan_gemm<1><<<dim3(128), dim3(NTHR), 0, stream>>>(x, Vp, out);
        kan_reduce<<<dim3(2048), dim3(256), 0, stream>>>(out, skip_b, out, 1);
    }
}